// Round 9
// baseline (1185.352 us; speedup 1.0000x reference)
//
#include <hip/hip_runtime.h>
#include <math.h>

#define FD 128
#define NOUT 16
#define ALPHA_F 0.1f

typedef short short8 __attribute__((ext_vector_type(8)));
typedef float f32x4 __attribute__((ext_vector_type(4)));

// ---------- bf16 helpers (bit-level, RNE) ----------
__device__ __forceinline__ float bflo(unsigned u) { return __uint_as_float(u << 16); }
__device__ __forceinline__ float bfhi(unsigned u) { return __uint_as_float(u & 0xffff0000u); }
__device__ __forceinline__ unsigned f2bf(float f) {
    unsigned u = __float_as_uint(f);
    u += 0x7fffu + ((u >> 16) & 1u);          // round-to-nearest-even
    return u >> 16;
}
__device__ __forceinline__ unsigned pack2(float a, float b) {
    return f2bf(a) | (f2bf(b) << 16);
}

// ---------- CSC build ----------

__global__ void count_kernel(const int* __restrict__ cols, int* __restrict__ cnt, int e) {
    int i = blockIdx.x * blockDim.x + threadIdx.x;
    if (i < e) atomicAdd(&cnt[cols[i]], 1);
}

__global__ void dinv_kernel(const int* __restrict__ cnt, float* __restrict__ dinv, int n) {
    int i = blockIdx.x * blockDim.x + threadIdx.x;
    if (i < n) dinv[i] = rsqrtf((float)(cnt[i] + 1));   // +1 self-loop
}

// padded degree: true degree (cnt+1) rounded up to multiple of 8
__device__ __forceinline__ int padded(int cnt) { return (cnt + 8) & ~7; }

// three-kernel exclusive scan of padded degrees
__global__ void scan_partial_kernel(const int* __restrict__ cnt, int* __restrict__ bsum, int n) {
    __shared__ int sh[256];
    int base = blockIdx.x * 1024 + threadIdx.x * 4;
    int s = 0;
    #pragma unroll
    for (int j = 0; j < 4; ++j) { int i = base + j; if (i < n) s += padded(cnt[i]); }
    sh[threadIdx.x] = s; __syncthreads();
    for (int d = 128; d > 0; d >>= 1) {
        if ((int)threadIdx.x < d) sh[threadIdx.x] += sh[threadIdx.x + d];
        __syncthreads();
    }
    if (threadIdx.x == 0) bsum[blockIdx.x] = sh[0];
}

__global__ void scan_base_kernel(int* __restrict__ bsum, int* __restrict__ off, int nb, int n) {
    if (threadIdx.x == 0 && blockIdx.x == 0) {
        int run = 0;
        for (int b = 0; b < nb; ++b) { int t = bsum[b]; bsum[b] = run; run += t; }
        off[n] = run;
    }
}

// writes off[i] and cur[i]=off[i]. cnt and cur alias (read-before-write per thread).
__global__ void scan_final_kernel(const int* __restrict__ cnt, const int* __restrict__ bsum,
                                  int* __restrict__ off, int* __restrict__ cur, int n) {
    __shared__ int sh[256];
    int t = threadIdx.x;
    int base_i = blockIdx.x * 1024 + t * 4;
    int v[4]; int s = 0;
    #pragma unroll
    for (int j = 0; j < 4; ++j) { int i = base_i + j; v[j] = (i < n) ? padded(cnt[i]) : 0; s += v[j]; }
    sh[t] = s; __syncthreads();
    for (int d = 1; d < 256; d <<= 1) {
        int x = (t >= d) ? sh[t - d] : 0;
        __syncthreads();
        sh[t] += x;
        __syncthreads();
    }
    int excl = sh[t] - s + bsum[blockIdx.x];
    #pragma unroll
    for (int j = 0; j < 4; ++j) {
        int i = base_i + j;
        if (i < n) { off[i] = excl; cur[i] = excl; }
        excl += v[j];
    }
}

// edge record: low16 = src node id, high16 = bf16 weight
__global__ void fill_edges_kernel(const int* __restrict__ rows, const int* __restrict__ cols,
                                  const float* __restrict__ dinv, int* __restrict__ cur,
                                  unsigned* __restrict__ eg, int e) {
    int i = blockIdx.x * blockDim.x + threadIdx.x;
    if (i < e) {
        int r = rows[i];
        int c = cols[i];
        int pos = atomicAdd(&cur[c], 1);
        eg[pos] = (f2bf(dinv[r] * dinv[c]) << 16) | (unsigned)r;
    }
}

__global__ void fill_loops_kernel(const float* __restrict__ dinv, int* __restrict__ cur,
                                  unsigned* __restrict__ eg, int n) {
    int i = blockIdx.x * blockDim.x + threadIdx.x;
    if (i < n) {
        int pos = atomicAdd(&cur[i], 1);
        eg[pos] = (f2bf(dinv[i] * dinv[i]) << 16) | (unsigned)i;
    }
}

// ---------- pre-processing for MFMA GEMM ----------

// Wt[c][ku] = pack2(W[2ku][c], W[2ku+1][c]) : transposed, bf16-packed. 128x64 uints.
__global__ void wtrans_kernel(const float* __restrict__ W, unsigned* __restrict__ Wt) {
    int idx = blockIdx.x * 256 + threadIdx.x;
    if (idx < 128 * 64) {
        int c = idx >> 6, ku = idx & 63;
        Wt[idx] = pack2(W[(2 * ku) * FD + c], W[(2 * ku + 1) * FD + c]);
    }
}

// ---------- MFMA GEMM:  Y = X@W + b ; Ab = bf16(Y), Z0b = bf16(alpha*Y) ----------
// BF_IN=0: A read from fp32 (stage 1, RNE in-register convert); BF_IN=1: packed bf16.
template <int BF_IN>
__global__ __launch_bounds__(256, 4)
void gemm_mfma_kernel(const void* __restrict__ Xv, const unsigned* __restrict__ Wt,
                      const float* __restrict__ bias,
                      unsigned* __restrict__ Ab, unsigned* __restrict__ Z0b, int n) {
    int l = threadIdx.x & 63;
    int w = threadIdx.x >> 6;
    int l15 = l & 15, lq = l >> 4;
    int r0 = blockIdx.x * 64 + w * 16;
    int arow = min(r0 + l15, n - 1);
    const unsigned* bptr = Wt + (size_t)l15 * 64 + lq * 4;

    f32x4 acc[8];
    #pragma unroll
    for (int nt = 0; nt < 8; ++nt) acc[nt] = (f32x4){0.f, 0.f, 0.f, 0.f};

    #pragma unroll
    for (int kk = 0; kk < 4; ++kk) {
        short8 af;
        if (BF_IN) {
            const unsigned* aptr = (const unsigned*)Xv + (size_t)arow * 64 + lq * 4;
            af = *(const short8*)(aptr + kk * 16);
        } else {
            const float* ap = (const float*)Xv + (size_t)arow * FD + lq * 8 + kk * 32;
            float4 fa = *(const float4*)(ap);
            float4 fb = *(const float4*)(ap + 4);
            unsigned p0 = pack2(fa.x, fa.y), p1 = pack2(fa.z, fa.w);
            unsigned p2 = pack2(fb.x, fb.y), p3 = pack2(fb.z, fb.w);
            uint4 u = make_uint4(p0, p1, p2, p3);
            af = *(const short8*)&u;
        }
        #pragma unroll
        for (int nt = 0; nt < 8; ++nt) {
            short8 bf = *(const short8*)(bptr + nt * 1024 + kk * 16);
            acc[nt] = __builtin_amdgcn_mfma_f32_16x16x32_bf16(af, bf, acc[nt], 0, 0, 0);
        }
    }

    #pragma unroll
    for (int nt = 0; nt < 8; ++nt) {
        float b_ = bias[nt * 16 + l15];
        #pragma unroll
        for (int j = 0; j < 4; ++j) {
            float v = acc[nt][j] + b_;
            float vp = __shfl_xor(v, 1);
            int row = r0 + lq * 4 + j;
            if (!(l & 1) && row < n) {
                int cu = nt * 8 + (l15 >> 1);
                Ab[(size_t)row * 64 + cu]  = pack2(v, vp);
                Z0b[(size_t)row * 64 + cu] = pack2(ALPHA_F * v, ALPHA_F * vp);
            }
        }
    }
}

// ---------- APPNP step: Xout = 0.9*A_hat@Xin + Z0b, fp32 accum ----------
// 4 nodes per wave (16 lanes each, uint4 = 8 bf16 features per lane).
// Each gather instruction moves 1 KB/wave; 8 outstanding -> 64 KB/CU in flight.
// Padded degrees (mult of 8, zero-weight pads); dead groups replay their last
// chunk with zeroed weights (L2-warm lines, harmless).
#define ACC8(G, W_) { \
    a0 += W_ * bflo(G.x); a1 += W_ * bfhi(G.x); \
    a2 += W_ * bflo(G.y); a3 += W_ * bfhi(G.y); \
    a4 += W_ * bflo(G.z); a5 += W_ * bfhi(G.z); \
    a6 += W_ * bflo(G.w); a7 += W_ * bfhi(G.w); }

__global__ __launch_bounds__(256, 6)
void spmm_bf16_kernel(const int* __restrict__ off, const unsigned* __restrict__ eg,
                      const unsigned* __restrict__ Xin, const unsigned* __restrict__ X0b,
                      unsigned* __restrict__ Xout, int n, int relu) {
    int node = blockIdx.x * 16 + ((int)threadIdx.x >> 4);
    if (node >= n) return;
    int fu = threadIdx.x & 15;                     // uint4 index within row
    int s = off[node];
    int degpad = off[node + 1] - s;                // multiple of 8, >= 8
    int d1 = max(degpad, __shfl_xor(degpad, 16));
    int dm = max(d1, __shfl_xor(d1, 32));          // max over the 4 groups
    const uint4* Xg = (const uint4*)Xin;
    uint4 x0 = ((const uint4*)X0b)[(size_t)node * 16 + fu];   // issue early
    float a0 = 0.f, a1 = 0.f, a2 = 0.f, a3 = 0.f;
    float a4 = 0.f, a5 = 0.f, a6 = 0.f, a7 = 0.f;

    for (int base = 0; base < dm; base += 8) {
        int p = s + min(base, degpad - 8);
        bool live = base < degpad;
        uint4 ra = *(const uint4*)(eg + p);        // 8 records, broadcast in group
        uint4 rb = *(const uint4*)(eg + p + 4);
        uint4 g0 = Xg[(ra.x & 0xffffu) * 16u + fu];
        uint4 g1 = Xg[(ra.y & 0xffffu) * 16u + fu];
        uint4 g2 = Xg[(ra.z & 0xffffu) * 16u + fu];
        uint4 g3 = Xg[(ra.w & 0xffffu) * 16u + fu];
        uint4 g4 = Xg[(rb.x & 0xffffu) * 16u + fu];
        uint4 g5 = Xg[(rb.y & 0xffffu) * 16u + fu];
        uint4 g6 = Xg[(rb.z & 0xffffu) * 16u + fu];
        uint4 g7 = Xg[(rb.w & 0xffffu) * 16u + fu];
        float w0 = live ? bfhi(ra.x) : 0.f;
        float w1 = live ? bfhi(ra.y) : 0.f;
        float w2 = live ? bfhi(ra.z) : 0.f;
        float w3 = live ? bfhi(ra.w) : 0.f;
        float w4 = live ? bfhi(rb.x) : 0.f;
        float w5 = live ? bfhi(rb.y) : 0.f;
        float w6 = live ? bfhi(rb.z) : 0.f;
        float w7 = live ? bfhi(rb.w) : 0.f;
        ACC8(g0, w0) ACC8(g1, w1) ACC8(g2, w2) ACC8(g3, w3)
        ACC8(g4, w4) ACC8(g5, w5) ACC8(g6, w6) ACC8(g7, w7)
    }

    float v0 = 0.9f * a0 + bflo(x0.x);
    float v1 = 0.9f * a1 + bfhi(x0.x);
    float v2 = 0.9f * a2 + bflo(x0.y);
    float v3 = 0.9f * a3 + bfhi(x0.y);
    float v4 = 0.9f * a4 + bflo(x0.z);
    float v5 = 0.9f * a5 + bfhi(x0.z);
    float v6 = 0.9f * a6 + bflo(x0.w);
    float v7 = 0.9f * a7 + bfhi(x0.w);
    if (relu) {
        v0 = fmaxf(v0, 0.f); v1 = fmaxf(v1, 0.f);
        v2 = fmaxf(v2, 0.f); v3 = fmaxf(v3, 0.f);
        v4 = fmaxf(v4, 0.f); v5 = fmaxf(v5, 0.f);
        v6 = fmaxf(v6, 0.f); v7 = fmaxf(v7, 0.f);
    }
    uint4 o;
    o.x = pack2(v0, v1); o.y = pack2(v2, v3);
    o.z = pack2(v4, v5); o.w = pack2(v6, v7);
    ((uint4*)Xout)[(size_t)node * 16 + fu] = o;
}

// ---------- head: logits = H @ Wc + bc ; log_softmax. 16 lanes/node ----------
__global__ void head_kernel(const unsigned* __restrict__ Hb, const float* __restrict__ Wc,
                            const float* __restrict__ bc, float* __restrict__ out, int n) {
    int t = threadIdx.x;
    int o = t & (NOUT - 1);
    int node = blockIdx.x * (256 / NOUT) + (t >> 4);
    if (node >= n) return;
    float acc = bc[o];
    const uint4* hrow = (const uint4*)(Hb + (size_t)node * 64);
    #pragma unroll 4
    for (int k4 = 0; k4 < 16; ++k4) {
        uint4 u = hrow[k4];
        int k = k4 * 8;
        acc += bflo(u.x) * Wc[(k + 0) * NOUT + o];
        acc += bfhi(u.x) * Wc[(k + 1) * NOUT + o];
        acc += bflo(u.y) * Wc[(k + 2) * NOUT + o];
        acc += bfhi(u.y) * Wc[(k + 3) * NOUT + o];
        acc += bflo(u.z) * Wc[(k + 4) * NOUT + o];
        acc += bfhi(u.z) * Wc[(k + 5) * NOUT + o];
        acc += bflo(u.w) * Wc[(k + 6) * NOUT + o];
        acc += bfhi(u.w) * Wc[(k + 7) * NOUT + o];
    }
    float m = acc;
    #pragma unroll
    for (int d = NOUT / 2; d > 0; d >>= 1) m = fmaxf(m, __shfl_xor(m, d, NOUT));
    float ex = __expf(acc - m);
    float s = ex;
    #pragma unroll
    for (int d = NOUT / 2; d > 0; d >>= 1) s += __shfl_xor(s, d, NOUT);
    out[node * NOUT + o] = acc - m - __logf(s);
}

// ---------- launch ----------

static inline size_t align256(size_t x) { return (x + 255) & ~(size_t)255; }

extern "C" void kernel_launch(void* const* d_in, const int* in_sizes, int n_in,
                              void* d_out, int out_size, void* d_ws, size_t ws_size,
                              hipStream_t stream) {
    const float* x  = (const float*)d_in[0];
    const int*   ei = (const int*)d_in[1];
    const float* W1 = (const float*)d_in[2];
    const float* b1 = (const float*)d_in[3];
    const float* W2 = (const float*)d_in[4];
    const float* b2 = (const float*)d_in[5];
    const float* W3 = (const float*)d_in[6];
    const float* b3 = (const float*)d_in[7];
    const float* Wc = (const float*)d_in[8];
    const float* bc = (const float*)d_in[9];
    float* out = (float*)d_out;

    const int n = in_sizes[0] / FD;       // 50000
    const int e = in_sizes[1] / 2;        // 800000
    const int nnz_max = e + n + 8 * n + 16;   // padded upper bound
    const int nb = (n + 1023) / 1024;

    const int* rows = ei;
    const int* cols = ei + e;

    // workspace layout (~57 MB)
    char* p = (char*)d_ws;
    int*      off  = (int*)p;       p += align256((size_t)(n + 1) * 4);
    int*      cur  = (int*)p;       p += align256((size_t)n * 4);
    float*    dinv = (float*)p;     p += align256((size_t)n * 4);
    int*      bsum = (int*)p;       p += align256((size_t)nb * 4);
    unsigned* eg   = (unsigned*)p;  p += align256((size_t)nnz_max * 4);
    unsigned* Wt   = (unsigned*)p;  p += align256((size_t)3 * 8192 * 4);
    unsigned* Ab   = (unsigned*)p;  p += align256((size_t)n * 64 * 4);
    unsigned* Bb   = (unsigned*)p;  p += align256((size_t)n * 64 * 4);
    unsigned* Z0b  = (unsigned*)p;  p += align256((size_t)n * 64 * 4);
    unsigned* Hb   = (unsigned*)p;  p += align256((size_t)n * 64 * 4);

    // ---- build padded CSC ----
    hipMemsetAsync(cur, 0, (size_t)n * 4, stream);
    hipMemsetAsync(eg, 0, (size_t)nnz_max * 4, stream);
    count_kernel<<<(e + 255) / 256, 256, 0, stream>>>(cols, cur, e);
    dinv_kernel<<<(n + 255) / 256, 256, 0, stream>>>(cur, dinv, n);
    scan_partial_kernel<<<nb, 256, 0, stream>>>(cur, bsum, n);
    scan_base_kernel<<<1, 64, 0, stream>>>(bsum, off, nb, n);
    scan_final_kernel<<<nb, 256, 0, stream>>>(cur, bsum, off, cur, n);
    fill_edges_kernel<<<(e + 255) / 256, 256, 0, stream>>>(rows, cols, dinv, cur, eg, e);
    fill_loops_kernel<<<(n + 255) / 256, 256, 0, stream>>>(dinv, cur, eg, n);

    // ---- weight transpose ----
    wtrans_kernel<<<32, 256, 0, stream>>>(W1, Wt);
    wtrans_kernel<<<32, 256, 0, stream>>>(W2, Wt + 8192);
    wtrans_kernel<<<32, 256, 0, stream>>>(W3, Wt + 16384);

    const int gemm_grid = (n + 63) / 64;
    const int spmm_grid = (n + 15) / 16;
    const float* bl[3] = { b1, b2, b3 };
    const void* gin = x;

    for (int st = 0; st < 3; ++st) {
        if (st == 0)
            gemm_mfma_kernel<0><<<gemm_grid, 256, 0, stream>>>(gin, Wt, bl[st], Ab, Z0b, n);
        else
            gemm_mfma_kernel<1><<<gemm_grid, 256, 0, stream>>>(gin, Wt + st * 8192, bl[st], Ab, Z0b, n);
        unsigned* bufs[2] = { Ab, Bb };
        int cu = 0;
        for (int k = 0; k < 10; ++k) {
            unsigned* o_ = (k == 9) ? Hb : bufs[cu ^ 1];
            spmm_bf16_kernel<<<spmm_grid, 256, 0, stream>>>(off, eg, bufs[cu], Z0b, o_, n, k == 9);
            cu ^= 1;
        }
        gin = Hb;
    }

    head_kernel<<<(n + 15) / 16, 256, 0, stream>>>(Hb, Wc, bc, out, n);
}